// Round 2
// baseline (3496.017 us; speedup 1.0000x reference)
//
#include <hip/hip_runtime.h>
#include <hip/hip_bf16.h>
#include <math.h>

typedef unsigned short u16;
typedef unsigned int   u32;
typedef __bf16 bf16x8_t __attribute__((ext_vector_type(8)));
typedef float  f32x4_t  __attribute__((ext_vector_type(4)));

#define DEVI static __device__ __forceinline__

DEVI float bf2f(u16 u){ union{u32 i; float f;} v; v.i = ((u32)u)<<16; return v.f; }
DEVI u16 f2bf(float f){ union{float f; u32 i;} v; v.f = f; u32 i = v.i; i += 0x7fffu + ((i>>16)&1u); return (u16)(i>>16); }
DEVI float sigm(float x){ return 1.0f/(1.0f + __expf(-x)); }
DEVI float silu_(float x){ return x * sigm(x); }

constexpr int L_=2048, B_=8, D_=1024, Z_=128, H_=2048, N_=16;
constexpr int MXC_  = 4224;          // D + Z + H + D
constexpr int CH_   = 128, NC_ = 16; // EMA chunking

// ---- workspace layout (bytes) — peak ~113 MB ----
constexpr size_t OFF_XN   = 0;             // [16384][1024] bf16   33.5MB
constexpr size_t OFF_MX   = 33554432;      // [16384][1024] bf16   33.5MB
constexpr size_t OFF_V    = 67108864;      // per-b [2048][2048] bf16 8.4MB
constexpr size_t OFF_R    = 75497472;      // per-b [2048][2048] bf16 8.4MB
constexpr size_t OFF_ATTN = 83886080;      // per-b [2048][2048] bf16 8.4MB
constexpr size_t OFF_HR   = 92274688;      // per-b [2048][2048] bf16 8.4MB
constexpr size_t OFF_U    = 100663296;     // per-b [2048][1024] bf16 4.2MB
constexpr size_t OFF_HX   = 104857600;     // per-b [2048][1024] bf16 4.2MB
constexpr size_t OFF_Q    = 109051904;     // per-b [2048][128] bf16 0.5MB
constexpr size_t OFF_K    = 109576192;     // per-b [2048][128] bf16 0.5MB
constexpr size_t OFF_EQ   = 110100480;     // [1024][16] f32
constexpr size_t OFF_EW   = 110166016;     // [1024][16] f32
constexpr size_t OFF_EP   = 110231552;     // [1024][16] f32
constexpr size_t OFF_F    = 110297088;     // [16][8][1024][16] f32 8.4MB (aliased F/CY)
// total = 118,685,696 bytes

// ---------------- LayerNorm (f32 in -> bf16 out) ----------------
__global__ __launch_bounds__(256) void k_ln(const float* __restrict__ x,
                                            const float* __restrict__ w,
                                            const float* __restrict__ b,
                                            u16* __restrict__ xn){
  int row = blockIdx.x, t = threadIdx.x;
  const float4* xr = (const float4*)(x + (size_t)row*D_);
  float4 v = xr[t];
  float s  = v.x+v.y+v.z+v.w;
  float sq = v.x*v.x+v.y*v.y+v.z*v.z+v.w*v.w;
  #pragma unroll
  for (int m=1; m<64; m<<=1){ s += __shfl_xor(s, m); sq += __shfl_xor(sq, m); }
  __shared__ float ss[4], sv[4];
  int wv = t>>6;
  if ((t&63)==0){ ss[wv]=s; sv[wv]=sq; }
  __syncthreads();
  s = ss[0]+ss[1]+ss[2]+ss[3]; sq = sv[0]+sv[1]+sv[2]+sv[3];
  float mu = s*(1.0f/D_);
  float var = sq*(1.0f/D_) - mu*mu;
  float rs = rsqrtf(var + 1e-5f);
  float4 wv4 = ((const float4*)w)[t];
  float4 bv4 = ((const float4*)b)[t];
  u16 o0 = f2bf((v.x-mu)*rs*wv4.x+bv4.x);
  u16 o1 = f2bf((v.y-mu)*rs*wv4.y+bv4.y);
  u16 o2 = f2bf((v.z-mu)*rs*wv4.z+bv4.z);
  u16 o3 = f2bf((v.w-mu)*rs*wv4.w+bv4.w);
  *(uint2*)(xn + (size_t)row*D_ + t*4) =
      make_uint2((u32)o0 | ((u32)o1<<16), (u32)o2 | ((u32)o3<<16));
}

// ---------------- EMA params ----------------
__global__ void k_ema_params(const float* __restrict__ delta, const float* __restrict__ alpha,
                             const float* __restrict__ beta,  const float* __restrict__ gamma,
                             float* __restrict__ qA, float* __restrict__ wcA, float* __restrict__ qPA){
  int i = blockIdx.x*256 + threadIdx.x;
  if (i >= D_*N_) return;
  float p = 1.0f/(1.0f + expf(-delta[i]));
  float q = 1.0f - p*(1.0f/(1.0f + expf(-alpha[i])));
  qA[i]  = q;
  wcA[i] = p*beta[i]*gamma[i]*0.25f;   // scale = 1/sqrt(16)
  qPA[i] = powf(q, (float)CH_);
}

// ---------------- EMA phase A: chunk-local finals ----------------
__global__ __launch_bounds__(256) void k_ema_a(const u16* __restrict__ xn,
                                               const float* __restrict__ qA,
                                               float* __restrict__ F){
  int d = blockIdx.x*256 + threadIdx.x;
  int b = blockIdx.y, c = blockIdx.z;
  float q[N_], s[N_];
  #pragma unroll
  for (int n=0;n<N_;n++){ q[n]=qA[d*N_+n]; s[n]=0.0f; }
  for (int t=0;t<CH_;t++){
    int l = c*CH_ + t;
    float x = bf2f(xn[((size_t)l*B_ + b)*D_ + d]);
    #pragma unroll
    for (int n=0;n<N_;n++) s[n] = q[n]*s[n] + x;
  }
  float* Fo = F + (((size_t)c*B_ + b)*D_ + d)*N_;
  #pragma unroll
  for (int n=0;n<N_;n++) Fo[n] = s[n];
}

// ---------------- EMA phase B: carries across chunks (CY aliases F) ----------------
__global__ __launch_bounds__(256) void k_ema_b(float* __restrict__ F,
                                               const float* __restrict__ qPA){
  int i = blockIdx.x*256 + threadIdx.x;   // over B*D*N = 131072
  int n = i & (N_-1);
  int d = (i>>4) & (D_-1);
  int b = i >> 14;
  float qP = qPA[d*N_+n];
  float S = 0.0f;
  for (int c=0;c<NC_;c++){
    size_t idx = (((size_t)c*B_ + b)*D_ + d)*N_ + n;
    float f = F[idx];        // read BEFORE overwrite (F/CY aliased)
    F[idx] = S;
    S = qP*S + f;
  }
}

// ---------------- EMA phase C: full output ----------------
__global__ __launch_bounds__(256) void k_ema_c(const u16* __restrict__ xn,
                                               const float* __restrict__ qA,
                                               const float* __restrict__ wcA,
                                               const float* __restrict__ CY,
                                               const float* __restrict__ omega,
                                               u16* __restrict__ mx){
  int d = blockIdx.x*256 + threadIdx.x;
  int b = blockIdx.y, c = blockIdx.z;
  float q[N_], wc[N_], s[N_];
  const float* cy = CY + (((size_t)c*B_ + b)*D_ + d)*N_;
  #pragma unroll
  for (int n=0;n<N_;n++){ q[n]=qA[d*N_+n]; wc[n]=wcA[d*N_+n]; s[n]=cy[n]; }
  float om = omega[d];
  for (int t=0;t<CH_;t++){
    int l = c*CH_ + t;
    float x = bf2f(xn[((size_t)l*B_ + b)*D_ + d]);
    float acc = 0.0f;
    #pragma unroll
    for (int n=0;n<N_;n++){ s[n] = q[n]*s[n] + x; acc += wc[n]*s[n]; }
    mx[((size_t)l*B_ + b)*D_ + d] = f2bf(silu_(acc + x*om));
  }
}

// ---------------- GEMM ----------------
// A: [M][K] bf16 (lda). W: BSRC 0 = bf16 [K][N], 1 = f32 [K][N], 2 = bf16 [N][K].
// M = gridDim.y*128, N = gridDim.x*128.
// ACT: 0 plain->C, 1 silu->C, 2 laplace(acc/L + relpos)->C,
//      3 base-split->(U,Q,K,R,HX), 5 (acc)*r->C, 6 final combine->outf (f32)
template<int BSRC, int ACT>
__global__ __launch_bounds__(256) void k_gemm(
    const u16* __restrict__ A, int lda,
    const void* __restrict__ W, int ldb, int K,
    u16* __restrict__ C, int ldc,
    const float* __restrict__ bias,
    const float* __restrict__ relpos,
    const u16* __restrict__ Rb,
    const float* __restrict__ qkg, const float* __restrict__ qkb,
    u16* __restrict__ Ub, u16* __restrict__ HXb, u16* __restrict__ Rbo,
    u16* __restrict__ Qb, u16* __restrict__ Kb,
    const u16* __restrict__ HXr, const u16* __restrict__ Ur,
    const float* __restrict__ xin, float* __restrict__ outf, int bb)
{
  __shared__ u16 Al[128][72];
  __shared__ u16 Bl[128][72];
  int rowBase = blockIdx.y*128;
  int colBase = blockIdx.x*128;
  int tid = threadIdx.x;
  int lane = tid & 63, wave = tid >> 6;
  int wm = (wave>>1)*64, wn = (wave&1)*64;

  f32x4_t acc[4][4];
  #pragma unroll
  for (int i=0;i<4;i++)
    #pragma unroll
    for (int j=0;j<4;j++) acc[i][j] = (f32x4_t){0.f,0.f,0.f,0.f};

  int atc = tid & 15, atr = tid >> 4;   // A / B-trans staging
  int btn = tid & 31, btk = tid >> 5;   // B [K][N] staging

  for (int k0 = 0; k0 < K; k0 += 64) {
    #pragma unroll
    for (int it=0; it<8; ++it) {
      int r = atr + it*16;
      *(uint2*)&Al[r][atc*4] = *(const uint2*)&A[(size_t)(rowBase+r)*lda + k0 + atc*4];
    }
    if (BSRC == 2) {
      const u16* Wb = (const u16*)W;
      #pragma unroll
      for (int it=0; it<8; ++it) {
        int r = atr + it*16;
        *(uint2*)&Bl[r][atc*4] = *(const uint2*)&Wb[(size_t)(colBase+r)*ldb + k0 + atc*4];
      }
    } else if (BSRC == 0) {
      const u16* Wb = (const u16*)W;
      #pragma unroll
      for (int it=0; it<8; ++it) {
        int kk = btk + it*8;
        uint2 v = *(const uint2*)&Wb[(size_t)(k0+kk)*ldb + colBase + btn*4];
        Bl[btn*4+0][kk] = (u16)(v.x & 0xffff);
        Bl[btn*4+1][kk] = (u16)(v.x >> 16);
        Bl[btn*4+2][kk] = (u16)(v.y & 0xffff);
        Bl[btn*4+3][kk] = (u16)(v.y >> 16);
      }
    } else {
      const float* Wf = (const float*)W;
      #pragma unroll
      for (int it=0; it<8; ++it) {
        int kk = btk + it*8;
        float4 v = *(const float4*)&Wf[(size_t)(k0+kk)*ldb + colBase + btn*4];
        Bl[btn*4+0][kk] = f2bf(v.x);
        Bl[btn*4+1][kk] = f2bf(v.y);
        Bl[btn*4+2][kk] = f2bf(v.z);
        Bl[btn*4+3][kk] = f2bf(v.w);
      }
    }
    __syncthreads();
    #pragma unroll
    for (int kk=0; kk<2; ++kk) {
      bf16x8_t af[4], bfr[4];
      int kf = kk*32 + (lane>>4)*8;
      #pragma unroll
      for (int i=0;i<4;i++) af[i] = *(const bf16x8_t*)&Al[wm + i*16 + (lane&15)][kf];
      #pragma unroll
      for (int j=0;j<4;j++) bfr[j] = *(const bf16x8_t*)&Bl[wn + j*16 + (lane&15)][kf];
      #pragma unroll
      for (int i=0;i<4;i++)
        #pragma unroll
        for (int j=0;j<4;j++)
          acc[i][j] = __builtin_amdgcn_mfma_f32_16x16x32_bf16(af[i], bfr[j], acc[i][j], 0,0,0);
    }
    __syncthreads();
  }

  #pragma unroll
  for (int i=0;i<4;i++) {
    #pragma unroll
    for (int j=0;j<4;j++) {
      int col = colBase + wn + j*16 + (lane&15);
      float bv = bias ? bias[col] : 0.0f;
      #pragma unroll
      for (int r2=0;r2<4;r2++) {
        int row = rowBase + wm + i*16 + (lane>>4)*4 + r2;
        float v = acc[i][j][r2] + bv;
        if (ACT == 0) {
          C[(size_t)row*ldc + col] = f2bf(v);
        } else if (ACT == 1) {
          C[(size_t)row*ldc + col] = f2bf(silu_(v));
        } else if (ACT == 2) {
          v = v*(1.0f/(float)L_) + relpos[2047 + col - row];
          v = 0.5f*(1.0f + erff((v - 0.707107f)*2.5066282746f));
          C[(size_t)row*ldc + col] = f2bf(v);
        } else if (ACT == 5) {
          v *= bf2f(Rb[(size_t)row*ldc + col]);
          C[(size_t)row*ldc + col] = f2bf(v);
        } else if (ACT == 3) {
          if (col < 1024) {
            Ub[(size_t)row*1024 + col] = f2bf(sigm(v));
          } else if (col < 1152) {
            float s = silu_(v);
            int zi = col - 1024;
            Qb[(size_t)row*128 + zi] = f2bf(s*qkg[zi]     + qkb[zi]);
            Kb[(size_t)row*128 + zi] = f2bf(s*qkg[128+zi] + qkb[128+zi]);
          } else if (col < 3200) {
            Rbo[(size_t)row*2048 + (col-1152)] = f2bf(silu_(v));
          } else {
            HXb[(size_t)row*1024 + (col-3200)] = f2bf(v);
          }
        } else if (ACT == 6) {
          float hx = bf2f(HXr[(size_t)row*1024 + col]);
          float hval = silu_(hx + v);
          size_t gi = ((size_t)row*B_ + bb)*D_ + col;
          float xv = xin[gi];
          float uu = bf2f(Ur[(size_t)row*1024 + col]);
          outf[gi] = xv + uu*(hval - xv);
        }
      }
    }
  }
}

extern "C" void kernel_launch(void* const* d_in, const int* in_sizes, int n_in,
                              void* d_out, int out_size, void* d_ws, size_t ws_size,
                              hipStream_t stream) {
  const float* x      = (const float*)d_in[0];
  const float* delta  = (const float*)d_in[1];
  const float* alpha  = (const float*)d_in[2];
  const float* betaE  = (const float*)d_in[3];
  const float* gammaE = (const float*)d_in[4];
  const float* omega  = (const float*)d_in[5];
  const float* v_w    = (const float*)d_in[6];
  const float* v_b    = (const float*)d_in[7];
  const float* mx_w   = (const float*)d_in[8];
  const float* mx_b   = (const float*)d_in[9];
  const float* h_w    = (const float*)d_in[10];
  const float* h_b    = (const float*)d_in[11];
  const float* qkg    = (const float*)d_in[12];
  const float* qkb    = (const float*)d_in[13];
  const float* relpos = (const float*)d_in[14];
  const float* ln_w   = (const float*)d_in[15];
  const float* ln_b   = (const float*)d_in[16];
  float* out = (float*)d_out;

  char* ws = (char*)d_ws;
  u16* XN   = (u16*)(ws + OFF_XN);
  u16* MX   = (u16*)(ws + OFF_MX);
  u16* Vb   = (u16*)(ws + OFF_V);
  u16* Rb   = (u16*)(ws + OFF_R);
  u16* ATTN = (u16*)(ws + OFF_ATTN);
  u16* HRb  = (u16*)(ws + OFF_HR);
  u16* Ub   = (u16*)(ws + OFF_U);
  u16* HXb  = (u16*)(ws + OFF_HX);
  u16* Qb   = (u16*)(ws + OFF_Q);
  u16* Kb   = (u16*)(ws + OFF_K);
  float* EQ = (float*)(ws + OFF_EQ);
  float* EW = (float*)(ws + OFF_EW);
  float* EP = (float*)(ws + OFF_EP);
  float* Ff = (float*)(ws + OFF_F);

  // 1. LayerNorm
  k_ln<<<L_*B_, 256, 0, stream>>>(x, ln_w, ln_b, XN);
  // 2. EMA (blocked scan)
  k_ema_params<<<(D_*N_+255)/256, 256, 0, stream>>>(delta, alpha, betaE, gammaE, EQ, EW, EP);
  k_ema_a<<<dim3(D_/256, B_, NC_), 256, 0, stream>>>(XN, EQ, Ff);
  k_ema_b<<<(B_*D_*N_)/256, 256, 0, stream>>>(Ff, EP);
  k_ema_c<<<dim3(D_/256, B_, NC_), 256, 0, stream>>>(XN, EQ, EW, Ff, omega, MX);

  // 3. per-batch attention pipeline
  for (int b = 0; b < B_; ++b) {
    // v_b = silu(xn_b @ v_w + v_b)           [2048 x 2048, K=1024]
    k_gemm<1,1><<<dim3(H_/128, L_/128), 256, 0, stream>>>(
        XN + b*D_, B_*D_, v_w, H_, D_, Vb, H_, v_b,
        nullptr, nullptr, nullptr, nullptr,
        nullptr, nullptr, nullptr, nullptr, nullptr,
        nullptr, nullptr, nullptr, nullptr, 0);
    // base_b = mx_b @ mx_w + mx_b  -> split  [2048 x 4224, K=1024]
    k_gemm<1,3><<<dim3(MXC_/128, L_/128), 256, 0, stream>>>(
        MX + b*D_, B_*D_, mx_w, MXC_, D_, nullptr, 0, mx_b,
        nullptr, nullptr, qkg, qkb,
        Ub, HXb, Rb, Qb, Kb,
        nullptr, nullptr, nullptr, nullptr, 0);
    // attn = laplace(q@k^T / L + bias)       [2048 x 2048, K=128]
    k_gemm<2,2><<<dim3(L_/128, L_/128), 256, 0, stream>>>(
        Qb, Z_, Kb, Z_, Z_, ATTN, L_, nullptr,
        relpos, nullptr, nullptr, nullptr,
        nullptr, nullptr, nullptr, nullptr, nullptr,
        nullptr, nullptr, nullptr, nullptr, 0);
    // hr = (attn @ v_b) * r                  [2048 x 2048, K=2048]
    k_gemm<0,5><<<dim3(H_/128, L_/128), 256, 0, stream>>>(
        ATTN, L_, Vb, H_, L_, HRb, H_, nullptr,
        nullptr, Rb, nullptr, nullptr,
        nullptr, nullptr, nullptr, nullptr, nullptr,
        nullptr, nullptr, nullptr, nullptr, 0);
    // out_b = x + u*(silu(hx + hr@h_w + h_b) - x)   [2048 x 1024, K=2048]
    k_gemm<1,6><<<dim3(D_/128, L_/128), 256, 0, stream>>>(
        HRb, H_, h_w, D_, H_, nullptr, 0, h_b,
        nullptr, nullptr, nullptr, nullptr,
        nullptr, nullptr, nullptr, nullptr, nullptr,
        HXb, Ub, x, out, b);
  }
}

// Round 3
// 1009.821 us; speedup vs baseline: 3.4620x; 3.4620x over previous
//
#include <hip/hip_runtime.h>
#include <hip/hip_bf16.h>
#include <math.h>

typedef unsigned short u16;
typedef unsigned int   u32;
typedef __bf16 bf16x8_t __attribute__((ext_vector_type(8)));
typedef float  f32x4_t  __attribute__((ext_vector_type(4)));

#define DEVI static __device__ __forceinline__

DEVI float bf2f(u16 u){ union{u32 i; float f;} v; v.i = ((u32)u)<<16; return v.f; }
DEVI u16 f2bf(float f){ union{float f; u32 i;} v; v.f = f; u32 i = v.i; i += 0x7fffu + ((i>>16)&1u); return (u16)(i>>16); }
DEVI float sigm(float x){ return 1.0f/(1.0f + __expf(-x)); }
DEVI float silu_(float x){ return x * sigm(x); }

DEVI void gload16(const u16* gsrc, u16* lds){
  __builtin_amdgcn_global_load_lds(
      (const __attribute__((address_space(1))) unsigned int*)gsrc,
      (__attribute__((address_space(3))) unsigned int*)lds, 16, 0, 0);
}

constexpr int L_=2048, B_=8, D_=1024, Z_=128, H_=2048, N_=16;
constexpr int CH_=128, NC_=16;

// ---------------- LayerNorm (f32 -> bf16) ----------------
__global__ __launch_bounds__(256) void k_ln(const float* __restrict__ x,
                                            const float* __restrict__ w,
                                            const float* __restrict__ b,
                                            u16* __restrict__ xn){
  int row = blockIdx.x, t = threadIdx.x;
  const float4* xr = (const float4*)(x + (size_t)row*D_);
  float4 v = xr[t];
  float s  = v.x+v.y+v.z+v.w;
  float sq = v.x*v.x+v.y*v.y+v.z*v.z+v.w*v.w;
  #pragma unroll
  for (int m=1; m<64; m<<=1){ s += __shfl_xor(s, m); sq += __shfl_xor(sq, m); }
  __shared__ float ss[4], sv[4];
  int wv = t>>6;
  if ((t&63)==0){ ss[wv]=s; sv[wv]=sq; }
  __syncthreads();
  s = ss[0]+ss[1]+ss[2]+ss[3]; sq = sv[0]+sv[1]+sv[2]+sv[3];
  float mu = s*(1.0f/D_);
  float var = sq*(1.0f/D_) - mu*mu;
  float rs = rsqrtf(var + 1e-5f);
  float4 wv4 = ((const float4*)w)[t];
  float4 bv4 = ((const float4*)b)[t];
  u16 o0 = f2bf((v.x-mu)*rs*wv4.x+bv4.x);
  u16 o1 = f2bf((v.y-mu)*rs*wv4.y+bv4.y);
  u16 o2 = f2bf((v.z-mu)*rs*wv4.z+bv4.z);
  u16 o3 = f2bf((v.w-mu)*rs*wv4.w+bv4.w);
  *(uint2*)(xn + (size_t)row*D_ + t*4) =
      make_uint2((u32)o0 | ((u32)o1<<16), (u32)o2 | ((u32)o3<<16));
}

// ---------------- weight transpose: f32 [R][C] -> bf16 [C][R] ----------------
__global__ __launch_bounds__(256) void k_tr(const float* __restrict__ in, int R, int C,
                                            u16* __restrict__ out){
  __shared__ u16 TT[32*33];
  int c0 = blockIdx.x*32, r0 = blockIdx.y*32;
  int t = threadIdx.x;
  int lr = t>>3, lc4 = (t&7)*4;
  float4 v = *(const float4*)&in[(size_t)(r0+lr)*C + c0 + lc4];
  TT[(lc4+0)*33 + lr] = f2bf(v.x);
  TT[(lc4+1)*33 + lr] = f2bf(v.y);
  TT[(lc4+2)*33 + lr] = f2bf(v.z);
  TT[(lc4+3)*33 + lr] = f2bf(v.w);
  __syncthreads();
  int orr = t>>3, oc4 = (t&7)*4;
  u16 a0 = TT[orr*33 + oc4+0], a1 = TT[orr*33 + oc4+1];
  u16 a2 = TT[orr*33 + oc4+2], a3 = TT[orr*33 + oc4+3];
  *(uint2*)&out[(size_t)(c0+orr)*R + r0 + oc4] =
      make_uint2((u32)a0 | ((u32)a1<<16), (u32)a2 | ((u32)a3<<16));
}

// ---------------- EMA ----------------
__global__ void k_ema_params(const float* __restrict__ delta, const float* __restrict__ alpha,
                             const float* __restrict__ beta,  const float* __restrict__ gamma,
                             float* __restrict__ qA, float* __restrict__ wcA, float* __restrict__ qPA){
  int i = blockIdx.x*256 + threadIdx.x;
  if (i >= D_*N_) return;
  float p = 1.0f/(1.0f + expf(-delta[i]));
  float q = 1.0f - p*(1.0f/(1.0f + expf(-alpha[i])));
  qA[i]  = q;
  wcA[i] = p*beta[i]*gamma[i]*0.25f;
  qPA[i] = powf(q, (float)CH_);
}

__global__ __launch_bounds__(256) void k_ema_a(const u16* __restrict__ xn,
                                               const float* __restrict__ qA,
                                               float* __restrict__ F){
  int d = blockIdx.x*256 + threadIdx.x;
  int b = blockIdx.y, c = blockIdx.z;
  float q[N_], s[N_];
  #pragma unroll
  for (int n=0;n<N_;n++){ q[n]=qA[d*N_+n]; s[n]=0.0f; }
  for (int t=0;t<CH_;t++){
    int l = c*CH_ + t;
    float x = bf2f(xn[((size_t)l*B_ + b)*D_ + d]);
    #pragma unroll
    for (int n=0;n<N_;n++) s[n] = q[n]*s[n] + x;
  }
  float* Fo = F + (((size_t)c*B_ + b)*D_ + d)*N_;
  #pragma unroll
  for (int n=0;n<N_;n++) Fo[n] = s[n];
}

__global__ __launch_bounds__(256) void k_ema_b(float* __restrict__ F,
                                               const float* __restrict__ qPA){
  int i = blockIdx.x*256 + threadIdx.x;
  int n = i & (N_-1);
  int d = (i>>4) & (D_-1);
  int b = i >> 14;
  float qP = qPA[d*N_+n];
  float S = 0.0f;
  for (int c=0;c<NC_;c++){
    size_t idx = (((size_t)c*B_ + b)*D_ + d)*N_ + n;
    float f = F[idx];
    F[idx] = S;
    S = qP*S + f;
  }
}

__global__ __launch_bounds__(256) void k_ema_c(const u16* __restrict__ xn,
                                               const float* __restrict__ qA,
                                               const float* __restrict__ wcA,
                                               const float* __restrict__ CY,
                                               const float* __restrict__ omega,
                                               u16* __restrict__ mx){
  int d = blockIdx.x*256 + threadIdx.x;
  int b = blockIdx.y, c = blockIdx.z;
  float q[N_], wc[N_], s[N_];
  const float* cy = CY + (((size_t)c*B_ + b)*D_ + d)*N_;
  #pragma unroll
  for (int n=0;n<N_;n++){ q[n]=qA[d*N_+n]; wc[n]=wcA[d*N_+n]; s[n]=cy[n]; }
  float om = omega[d];
  for (int t=0;t<CH_;t++){
    int l = c*CH_ + t;
    float x = bf2f(xn[((size_t)l*B_ + b)*D_ + d]);
    float acc = 0.0f;
    #pragma unroll
    for (int n=0;n<N_;n++){ s[n] = q[n]*s[n] + x; acc += wc[n]*s[n]; }
    mx[((size_t)l*B_ + b)*D_ + d] = f2bf(silu_(acc + x*om));
  }
}

// ---------------- GEMM (m97 structure): A[M][K] x B[N][K], gload_lds staging ----
// OP0: VT = silu(acc + biasR[row])             (v GEMM computed as C^T)
// OP1: base split -> U(P0), HX(P1), Q(P2), K(P3), R(C)
// OP2: attn = laplace(acc/L + relpos)
// OP3: HR = acc * R
// OP4: out = x + u*(silu(hx + acc + bias) - x)   (f32 out)
template<int OP>
__global__ __launch_bounds__(256) void k_gemm(
    const u16* __restrict__ A, int lda, long aStr,
    const u16* __restrict__ Bm, int ldb, long bStr,
    int K,
    u16* __restrict__ C, int ldc, long cStr,
    const float* __restrict__ biasC, const float* __restrict__ biasR,
    const float* __restrict__ relpos,
    const float* __restrict__ qkg, const float* __restrict__ qkb,
    u16* __restrict__ P0, u16* __restrict__ P1,
    u16* __restrict__ P2, u16* __restrict__ P3,
    const u16* __restrict__ RP0, const u16* __restrict__ RP1,
    const float* __restrict__ xin, float* __restrict__ outf, int bb)
{
  __shared__ u16 Al[8192];
  __shared__ u16 Bl[8192];
  int zz = blockIdx.z;
  const u16* Ab = A + (size_t)zz*aStr;
  const u16* Bb = Bm + (size_t)zz*bStr;
  int rowBase = blockIdx.y*128;
  int colBase = blockIdx.x*128;
  int tid = threadIdx.x;
  int lane = tid & 63, wave = tid >> 6;
  int wm = (wave>>1)*64, wn = (wave&1)*64;
  int lane15 = lane & 15, lane4 = lane >> 4;

  f32x4_t acc[4][4];
  #pragma unroll
  for (int i=0;i<4;i++)
    #pragma unroll
    for (int j=0;j<4;j++) acc[i][j] = (f32x4_t){0.f,0.f,0.f,0.f};

  for (int k0 = 0; k0 < K; k0 += 64) {
    #pragma unroll
    for (int it=0; it<4; ++it) {
      int c = it*256 + tid;
      gload16(Ab + (size_t)(rowBase + (c>>3))*lda + k0 + (c&7)*8, &Al[c*8]);
    }
    #pragma unroll
    for (int it=0; it<4; ++it) {
      int c = it*256 + tid;
      gload16(Bb + (size_t)(colBase + (c>>3))*ldb + k0 + (c&7)*8, &Bl[c*8]);
    }
    __syncthreads();
    #pragma unroll
    for (int kk=0; kk<2; ++kk) {
      bf16x8_t af[4], bfr[4];
      int kf = kk*32 + lane4*8;
      #pragma unroll
      for (int i=0;i<4;i++) af[i] = *(const bf16x8_t*)&Al[(wm + i*16 + lane15)*64 + kf];
      #pragma unroll
      for (int j=0;j<4;j++) bfr[j] = *(const bf16x8_t*)&Bl[(wn + j*16 + lane15)*64 + kf];
      #pragma unroll
      for (int i=0;i<4;i++)
        #pragma unroll
        for (int j=0;j<4;j++)
          acc[i][j] = __builtin_amdgcn_mfma_f32_16x16x32_bf16(af[i], bfr[j], acc[i][j], 0,0,0);
    }
    __syncthreads();
  }

  u16* Cb = C ? C + (size_t)zz*cStr : nullptr;
  u16* P0b = P0 ? P0 + (size_t)zz*(L_*(size_t)D_) : nullptr;
  u16* P1b = P1 ? P1 + (size_t)zz*(L_*(size_t)D_) : nullptr;
  u16* P2b = P2 ? P2 + (size_t)zz*(L_*(size_t)Z_) : nullptr;
  u16* P3b = P3 ? P3 + (size_t)zz*(L_*(size_t)Z_) : nullptr;
  const u16* RP0b = RP0 ? RP0 + (size_t)zz*(OP==3 ? (size_t)L_*H_ : (size_t)L_*D_) : nullptr;
  const u16* RP1b = RP1 ? RP1 + (size_t)zz*(L_*(size_t)D_) : nullptr;
  int bglob = bb + zz;

  #pragma unroll
  for (int i=0;i<4;i++) {
    #pragma unroll
    for (int j=0;j<4;j++) {
      int col = colBase + wn + j*16 + lane15;
      #pragma unroll
      for (int r2=0;r2<4;r2++) {
        int row = rowBase + wm + i*16 + lane4*4 + r2;
        float v = acc[i][j][r2];
        if (OP == 0) {
          Cb[(size_t)row*ldc + col] = f2bf(silu_(v + biasR[row]));
        } else if (OP == 1) {
          v += biasC[col];
          if (col < 1024) {
            P0b[(size_t)row*1024 + col] = f2bf(sigm(v));
          } else if (col < 1152) {
            float s = silu_(v);
            int zi = col - 1024;
            P2b[(size_t)row*128 + zi] = f2bf(s*qkg[zi]     + qkb[zi]);
            P3b[(size_t)row*128 + zi] = f2bf(s*qkg[128+zi] + qkb[128+zi]);
          } else if (col < 3200) {
            Cb[(size_t)row*2048 + (col-1152)] = f2bf(silu_(v));
          } else {
            P1b[(size_t)row*1024 + (col-3200)] = f2bf(v);
          }
        } else if (OP == 2) {
          v = v*(1.0f/(float)L_) + relpos[2047 + col - row];
          v = 0.5f*(1.0f + erff((v - 0.707107f)*2.5066282746f));
          Cb[(size_t)row*ldc + col] = f2bf(v);
        } else if (OP == 3) {
          v *= bf2f(RP0b[(size_t)row*ldc + col]);
          Cb[(size_t)row*ldc + col] = f2bf(v);
        } else {
          v += biasC[col];
          float hx = bf2f(RP0b[(size_t)row*1024 + col]);
          float hval = silu_(hx + v);
          size_t gi = ((size_t)row*B_ + bglob)*D_ + col;
          float xv = xin[gi];
          float uu = bf2f(RP1b[(size_t)row*1024 + col]);
          outf[gi] = xv + uu*(hval - xv);
        }
      }
    }
  }
}

extern "C" void kernel_launch(void* const* d_in, const int* in_sizes, int n_in,
                              void* d_out, int out_size, void* d_ws, size_t ws_size,
                              hipStream_t stream) {
  const float* x      = (const float*)d_in[0];
  const float* delta  = (const float*)d_in[1];
  const float* alpha  = (const float*)d_in[2];
  const float* betaE  = (const float*)d_in[3];
  const float* gammaE = (const float*)d_in[4];
  const float* omega  = (const float*)d_in[5];
  const float* v_w    = (const float*)d_in[6];
  const float* v_b    = (const float*)d_in[7];
  const float* mx_w   = (const float*)d_in[8];
  const float* mx_b   = (const float*)d_in[9];
  const float* h_w    = (const float*)d_in[10];
  const float* h_b    = (const float*)d_in[11];
  const float* qkg    = (const float*)d_in[12];
  const float* qkb    = (const float*)d_in[13];
  const float* relpos = (const float*)d_in[14];
  const float* ln_w   = (const float*)d_in[15];
  const float* ln_b   = (const float*)d_in[16];
  float* out = (float*)d_out;

  // choose largest NB in {8,4,2,1} that fits ws_size
  const size_t fixedB = 92733440ull;
  const size_t perNB  = 42991616ull;
  int NB = 8;
  while (NB > 1 && fixedB + (size_t)NB*perNB > ws_size) NB >>= 1;
  int NG = B_ / NB;

  char* ws = (char*)d_ws;
  size_t o = 0;
  auto alloc = [&](size_t sz){ size_t r = o; o += sz; return r; };
  u16* XN    = (u16*)(ws + alloc(33554432));
  u16* MX    = (u16*)(ws + alloc(33554432));
  u16* VWT   = (u16*)(ws + alloc(4194304));    // [H][D] bf16
  u16* MXWT  = (u16*)(ws + alloc(8650752));    // [4224][D] bf16
  u16* HWT   = (u16*)(ws + alloc(4194304));    // [D][H] bf16
  float* EQ  = (float*)(ws + alloc(65536));
  float* EW  = (float*)(ws + alloc(65536));
  float* EP  = (float*)(ws + alloc(65536));
  float* Ff  = (float*)(ws + alloc(8388608));
  u16* VT    = (u16*)(ws + alloc((size_t)NB*8388608));   // [NB][H][L]
  u16* ATTN  = (u16*)(ws + alloc((size_t)NB*8388608));   // [NB][L][L]
  u16* Rb    = (u16*)(ws + alloc((size_t)NB*8388608));   // [NB][L][H]
  u16* HRb   = (u16*)(ws + alloc((size_t)NB*8388608));   // [NB][L][H]
  u16* Ub    = (u16*)(ws + alloc((size_t)NB*4194304));   // [NB][L][D]
  u16* HXb   = (u16*)(ws + alloc((size_t)NB*4194304));   // [NB][L][D]
  u16* Qb    = (u16*)(ws + alloc((size_t)NB*524288));    // [NB][L][Z]
  u16* Kb    = (u16*)(ws + alloc((size_t)NB*524288));    // [NB][L][Z]

  // 1. LayerNorm
  k_ln<<<L_*B_, 256, 0, stream>>>(x, ln_w, ln_b, XN);
  // 2. EMA blocked scan
  k_ema_params<<<(D_*N_+255)/256, 256, 0, stream>>>(delta, alpha, betaE, gammaE, EQ, EW, EP);
  k_ema_a<<<dim3(D_/256, B_, NC_), 256, 0, stream>>>(XN, EQ, Ff);
  k_ema_b<<<(B_*D_*N_)/256, 256, 0, stream>>>(Ff, EP);
  k_ema_c<<<dim3(D_/256, B_, NC_), 256, 0, stream>>>(XN, EQ, EW, Ff, omega, MX);
  // 3. weight transposes f32[R][C] -> bf16[C][R]
  k_tr<<<dim3(H_/32, D_/32), 256, 0, stream>>>(v_w, D_, H_, VWT);
  k_tr<<<dim3(4224/32, D_/32), 256, 0, stream>>>(mx_w, D_, 4224, MXWT);
  k_tr<<<dim3(D_/32, H_/32), 256, 0, stream>>>(h_w, H_, D_, HWT);

  // 4. grouped per-batch pipeline
  for (int g = 0; g < NG; ++g) {
    int b0 = g*NB;
    // VT[zz][h][l] = silu(VWT @ XN_b^T + v_b[h])
    k_gemm<0><<<dim3(L_/128, H_/128, NB), 256, 0, stream>>>(
        VWT, D_, 0L, XN + b0*D_, B_*D_, (long)D_, D_,
        VT, L_, (long)H_*L_,
        nullptr, v_b, nullptr, nullptr, nullptr,
        nullptr, nullptr, nullptr, nullptr, nullptr, nullptr,
        nullptr, nullptr, 0);
    // base split
    k_gemm<1><<<dim3(4224/128, L_/128, NB), 256, 0, stream>>>(
        MX + b0*D_, B_*D_, (long)D_, MXWT, D_, 0L, D_,
        Rb, H_, (long)L_*H_,
        mx_b, nullptr, nullptr, qkg, qkb,
        Ub, HXb, Qb, Kb, nullptr, nullptr,
        nullptr, nullptr, 0);
    // attn = laplace(Q K^T / L + relbias)
    k_gemm<2><<<dim3(L_/128, L_/128, NB), 256, 0, stream>>>(
        Qb, Z_, (long)L_*Z_, Kb, Z_, (long)L_*Z_, Z_,
        ATTN, L_, (long)L_*L_,
        nullptr, nullptr, relpos, nullptr, nullptr,
        nullptr, nullptr, nullptr, nullptr, nullptr, nullptr,
        nullptr, nullptr, 0);
    // HR = (attn @ V) * R
    k_gemm<3><<<dim3(H_/128, L_/128, NB), 256, 0, stream>>>(
        ATTN, L_, (long)L_*L_, VT, L_, (long)H_*L_, L_,
        HRb, H_, (long)L_*H_,
        nullptr, nullptr, nullptr, nullptr, nullptr,
        nullptr, nullptr, nullptr, nullptr, Rb, nullptr,
        nullptr, nullptr, 0);
    // out = x + u*(silu(hx + HR @ h_w + h_b) - x)
    k_gemm<4><<<dim3(D_/128, L_/128, NB), 256, 0, stream>>>(
        HRb, H_, (long)L_*H_, HWT, H_, 0L, H_,
        nullptr, 0, 0L,
        h_b, nullptr, nullptr, nullptr, nullptr,
        nullptr, nullptr, nullptr, nullptr, HXb, Ub,
        x, out, b0);
  }
}